// Round 2
// baseline (50878.485 us; speedup 1.0000x reference)
//
#include <hip/hip_runtime.h>
#include <hip/hip_bf16.h>
#include <hip/hip_cooperative_groups.h>

namespace cg = cooperative_groups;

#define B_   64
#define S_   512
#define IN_  512
#define H_   1024
#define OUT_ 512
#define H3_  3072
#define TC_  32          // timesteps per chunk
#define TCL2 5
#define NCHUNK (S_ / TC_)
#define MC_  (B_ * TC_)  // 2048 rows per chunk
#define NROW (B_ * S_)

typedef float f32x4 __attribute__((ext_vector_type(4)));
typedef short bf16x8 __attribute__((ext_vector_type(8)));

// ---------------------------------------------------------------------------
// f32 -> bf16 cast, 4 elems/thread
// ---------------------------------------------------------------------------
__global__ __launch_bounds__(256) void cast_f32_to_bf16(const float* __restrict__ in,
                                                        __hip_bfloat16* __restrict__ out,
                                                        int n4) {
  int i = blockIdx.x * 256 + threadIdx.x;
  if (i >= n4) return;
  float4 v = ((const float4*)in)[i];
  out[4 * i + 0] = __float2bfloat16(v.x);
  out[4 * i + 1] = __float2bfloat16(v.y);
  out[4 * i + 2] = __float2bfloat16(v.z);
  out[4 * i + 3] = __float2bfloat16(v.w);
}

// ---------------------------------------------------------------------------
// gather chunk [B, TC, IN] from x [B, S, IN], cast to bf16
// ---------------------------------------------------------------------------
__global__ __launch_bounds__(256) void gather_cast_x(const float* __restrict__ x,
                                                     __hip_bfloat16* __restrict__ out, int t0) {
  int i = blockIdx.x * 256 + threadIdx.x;  // over B_*TC_*IN_/4
  int e = i * 4;
  int b = e >> 14;          // / (TC_*IN_)
  int rem = e & 16383;
  float4 v = *(const float4*)(x + (size_t)b * (S_ * IN_) + (size_t)t0 * IN_ + rem);
  out[e + 0] = __float2bfloat16(v.x);
  out[e + 1] = __float2bfloat16(v.y);
  out[e + 2] = __float2bfloat16(v.z);
  out[e + 3] = __float2bfloat16(v.w);
}

// ---------------------------------------------------------------------------
// C[M,N](f32) = A[M,K](bf16) @ B[N,K](bf16)^T + bias[N]
// 256 thr (4 waves), 128x128 tile, wave = 64x64 via 4x4 16x16x32 MFMA frags.
// REMAP: C row r -> (r>>TCL2)*S_ + t0 + (r & (TC_-1))   (chunk -> [B,S] rows)
// ---------------------------------------------------------------------------
template <bool REMAP>
__global__ __launch_bounds__(256) void gemm_nt_bias(const __hip_bfloat16* __restrict__ A,
                                                    const __hip_bfloat16* __restrict__ Bm,
                                                    const float* __restrict__ bias,
                                                    float* __restrict__ C, int M, int N, int K,
                                                    int t0) {
  const int lane = threadIdx.x & 63;
  const int w = threadIdx.x >> 6;
  const int wr = w >> 1, wc = w & 1;
  const int row0 = blockIdx.y * 128 + wr * 64;
  const int col0 = blockIdx.x * 128 + wc * 64;
  const int kl = (lane >> 4) * 8;
  const int m16 = lane & 15;
  f32x4 acc[4][4] = {};
  for (int k0 = 0; k0 < K; k0 += 32) {
    bf16x8 a[4], b[4];
#pragma unroll
    for (int i = 0; i < 4; ++i)
      a[i] = *(const bf16x8*)(A + (size_t)(row0 + i * 16 + m16) * K + k0 + kl);
#pragma unroll
    for (int j = 0; j < 4; ++j)
      b[j] = *(const bf16x8*)(Bm + (size_t)(col0 + j * 16 + m16) * K + k0 + kl);
#pragma unroll
    for (int i = 0; i < 4; ++i)
#pragma unroll
      for (int j = 0; j < 4; ++j)
        acc[i][j] = __builtin_amdgcn_mfma_f32_16x16x32_bf16(a[i], b[j], acc[i][j], 0, 0, 0);
  }
  const int rsub = (lane >> 4) * 4;
#pragma unroll
  for (int i = 0; i < 4; ++i) {
    int row = row0 + i * 16 + rsub;
#pragma unroll
    for (int j = 0; j < 4; ++j) {
      int col = col0 + j * 16 + m16;
      float bv = bias[col];
#pragma unroll
      for (int r = 0; r < 4; ++r) {
        int rr = row + r;
        int crow = REMAP ? ((rr >> TCL2) * S_ + t0 + (rr & (TC_ - 1))) : rr;
        C[(size_t)crow * N + col] = acc[i][j][r] + bv;
      }
    }
  }
}

// ---------------------------------------------------------------------------
// GRU scan for TC_ timesteps of one layer. Cooperative: 128 blocks x 256 thr.
// Phase A: z,r  (output [64 x 2048], each block 16 cols, wave = 16 M-rows)
// Phase B: g + h update (blocks 0..63, 16 cols each)
// xp: [B*TC_, 3H] f32 chunk-local (bias pre-added), row = b*TC_ + t
// ---------------------------------------------------------------------------
__global__ __launch_bounds__(256) void gru_scan_chunk(
    const float* __restrict__ xp, const float* __restrict__ h0, int layer, int t0,
    const __hip_bfloat16* __restrict__ Wh, float* __restrict__ h_f32,
    __hip_bfloat16* __restrict__ h_bf16, float* __restrict__ z_f32,
    __hip_bfloat16* __restrict__ rh_bf16, __hip_bfloat16* __restrict__ y,
    float* __restrict__ hid_out) {
  cg::grid_group grid = cg::this_grid();
  const int tid = threadIdx.x;
  const int lane = tid & 63;
  const int w = tid >> 6;
  const int bx = blockIdx.x;

  if (t0 == 0) {  // init h from h0[:, layer, :]
    for (int i = bx * 256 + tid; i < B_ * H_; i += 128 * 256) {
      int b = i >> 10, cc = i & (H_ - 1);
      float v = h0[((size_t)b * 2 + layer) * H_ + cc];
      h_f32[i] = v;
      h_bf16[i] = __float2bfloat16(v);
    }
  }
  grid.sync();

  const int kl = (lane >> 4) * 8;
  const int m16 = lane & 15;
  const int row0 = w * 16;
  const int arow = row0 + m16;
  const int rsub = (lane >> 4) * 4;

  for (int t = 0; t < TC_; ++t) {
    // ---- phase A: z, r ----
    {
      const int c = bx * 16 + m16;  // 0..2047
      f32x4 acc0 = {}, acc1 = {};
      const __hip_bfloat16* Ab = h_bf16 + (size_t)arow * H_;
      const __hip_bfloat16* Bb = Wh + (size_t)c * H_;
#pragma unroll
      for (int k0 = 0; k0 < H_; k0 += 64) {
        bf16x8 a0 = *(const bf16x8*)(Ab + k0 + kl);
        bf16x8 b0 = *(const bf16x8*)(Bb + k0 + kl);
        bf16x8 a1 = *(const bf16x8*)(Ab + k0 + 32 + kl);
        bf16x8 b1 = *(const bf16x8*)(Bb + k0 + 32 + kl);
        acc0 = __builtin_amdgcn_mfma_f32_16x16x32_bf16(a0, b0, acc0, 0, 0, 0);
        acc1 = __builtin_amdgcn_mfma_f32_16x16x32_bf16(a1, b1, acc1, 0, 0, 0);
      }
#pragma unroll
      for (int j = 0; j < 4; ++j) {
        int row = row0 + rsub + j;  // batch row 0..63
        float pre = acc0[j] + acc1[j] + xp[((size_t)(row * TC_ + t)) * H3_ + c];
        float s = 1.f / (1.f + expf(-pre));
        if (c < H_) {
          z_f32[row * H_ + c] = s;
        } else {
          int hc = c - H_;
          rh_bf16[row * H_ + hc] = __float2bfloat16(s * h_f32[row * H_ + hc]);
        }
      }
    }
    grid.sync();
    // ---- phase B: g + h update ----
    if (bx < 64) {
      const int c = bx * 16 + m16;  // 0..1023
      f32x4 acc0 = {}, acc1 = {};
      const __hip_bfloat16* Ab = rh_bf16 + (size_t)arow * H_;
      const __hip_bfloat16* Bb = Wh + (size_t)(2 * H_ + c) * H_;
#pragma unroll
      for (int k0 = 0; k0 < H_; k0 += 64) {
        bf16x8 a0 = *(const bf16x8*)(Ab + k0 + kl);
        bf16x8 b0 = *(const bf16x8*)(Bb + k0 + kl);
        bf16x8 a1 = *(const bf16x8*)(Ab + k0 + 32 + kl);
        bf16x8 b1 = *(const bf16x8*)(Bb + k0 + 32 + kl);
        acc0 = __builtin_amdgcn_mfma_f32_16x16x32_bf16(a0, b0, acc0, 0, 0, 0);
        acc1 = __builtin_amdgcn_mfma_f32_16x16x32_bf16(a1, b1, acc1, 0, 0, 0);
      }
#pragma unroll
      for (int j = 0; j < 4; ++j) {
        int row = row0 + rsub + j;
        float pre = acc0[j] + acc1[j] + xp[((size_t)(row * TC_ + t)) * H3_ + 2 * H_ + c];
        float gg = tanhf(pre);
        int idx = row * H_ + c;
        float zz = z_f32[idx];
        float hn = zz * h_f32[idx] + (1.f - zz) * gg;
        h_f32[idx] = hn;
        __hip_bfloat16 hb = __float2bfloat16(hn);
        h_bf16[idx] = hb;
        y[((size_t)(row * TC_ + t)) * H_ + c] = hb;
      }
    }
    grid.sync();
  }

  if (t0 + TC_ == S_) {  // final hidden state
    for (int i = bx * 256 + tid; i < B_ * H_; i += 128 * 256) {
      int b = i >> 10, cc = i & (H_ - 1);
      hid_out[((size_t)b * 2 + layer) * H_ + cc] = h_f32[i];
    }
  }
}

// ---------------------------------------------------------------------------
extern "C" void kernel_launch(void* const* d_in, const int* in_sizes, int n_in,
                              void* d_out, int out_size, void* d_ws, size_t ws_size,
                              hipStream_t stream) {
  const float* x   = (const float*)d_in[0];
  const float* h0  = (const float*)d_in[1];
  const float* Wx0 = (const float*)d_in[2];
  const float* Wh0 = (const float*)d_in[3];
  const float* bh0 = (const float*)d_in[4];
  const float* Wx1 = (const float*)d_in[5];
  const float* Wh1 = (const float*)d_in[6];
  const float* bh1 = (const float*)d_in[7];
  const float* Why = (const float*)d_in[8];
  const float* by  = (const float*)d_in[9];
  float* out = (float*)d_out;
  float* hid_out = out + (size_t)NROW * OUT_;

  char* ws = (char*)d_ws;
  size_t off = 0;
  auto alloc = [&](size_t bytes) {
    char* p = ws + off;
    off += (bytes + 255) & ~(size_t)255;
    return p;
  };
  __hip_bfloat16* wx0b = (__hip_bfloat16*)alloc((size_t)H3_ * IN_ * 2);
  __hip_bfloat16* wh0b = (__hip_bfloat16*)alloc((size_t)H3_ * H_ * 2);
  __hip_bfloat16* wx1b = (__hip_bfloat16*)alloc((size_t)H3_ * H_ * 2);
  __hip_bfloat16* wh1b = (__hip_bfloat16*)alloc((size_t)H3_ * H_ * 2);
  __hip_bfloat16* whyb = (__hip_bfloat16*)alloc((size_t)OUT_ * H_ * 2);
  float* h_f32_0           = (float*)alloc((size_t)B_ * H_ * 4);
  __hip_bfloat16* h_bf16_0 = (__hip_bfloat16*)alloc((size_t)B_ * H_ * 2);
  float* h_f32_1           = (float*)alloc((size_t)B_ * H_ * 4);
  __hip_bfloat16* h_bf16_1 = (__hip_bfloat16*)alloc((size_t)B_ * H_ * 2);
  float* z_f32             = (float*)alloc((size_t)B_ * H_ * 4);
  __hip_bfloat16* rh       = (__hip_bfloat16*)alloc((size_t)B_ * H_ * 2);
  __hip_bfloat16* x_bfc    = (__hip_bfloat16*)alloc((size_t)MC_ * IN_ * 2);
  __hip_bfloat16* y_c      = (__hip_bfloat16*)alloc((size_t)MC_ * H_ * 2);
  float* xp_c              = (float*)alloc((size_t)MC_ * H3_ * 4);
  (void)ws_size;  // total ~56 MB

  auto cast = [&](const float* in, __hip_bfloat16* o, size_t n) {
    cast_f32_to_bf16<<<dim3((unsigned)((n / 4 + 255) / 256)), dim3(256), 0, stream>>>(in, o,
                                                                                     (int)(n / 4));
  };
  cast(Wx0, wx0b, (size_t)H3_ * IN_);
  cast(Wh0, wh0b, (size_t)H3_ * H_);
  cast(Wx1, wx1b, (size_t)H3_ * H_);
  cast(Wh1, wh1b, (size_t)H3_ * H_);
  cast(Why, whyb, (size_t)OUT_ * H_);

  for (int c = 0; c < NCHUNK; ++c) {
    int t0 = c * TC_;
    gather_cast_x<<<dim3(MC_ * IN_ / 4 / 256), dim3(256), 0, stream>>>(x, x_bfc, t0);
    gemm_nt_bias<false><<<dim3(H3_ / 128, MC_ / 128), dim3(256), 0, stream>>>(
        x_bfc, wx0b, bh0, xp_c, MC_, H3_, IN_, 0);
    {
      int layer = 0;
      void* args[] = {(void*)&xp_c, (void*)&h0,       (void*)&layer, (void*)&t0,
                      (void*)&wh0b, (void*)&h_f32_0,  (void*)&h_bf16_0,
                      (void*)&z_f32, (void*)&rh,      (void*)&y_c,   (void*)&hid_out};
      hipLaunchCooperativeKernel((void*)gru_scan_chunk, dim3(128), dim3(256), args, 0, stream);
    }
    gemm_nt_bias<false><<<dim3(H3_ / 128, MC_ / 128), dim3(256), 0, stream>>>(
        y_c, wx1b, bh1, xp_c, MC_, H3_, H_, 0);
    {
      int layer = 1;
      void* args[] = {(void*)&xp_c, (void*)&h0,       (void*)&layer, (void*)&t0,
                      (void*)&wh1b, (void*)&h_f32_1,  (void*)&h_bf16_1,
                      (void*)&z_f32, (void*)&rh,      (void*)&y_c,   (void*)&hid_out};
      hipLaunchCooperativeKernel((void*)gru_scan_chunk, dim3(128), dim3(256), args, 0, stream);
    }
    gemm_nt_bias<true><<<dim3(OUT_ / 128, MC_ / 128), dim3(256), 0, stream>>>(
        y_c, whyb, by, out, MC_, OUT_, H_, t0);
  }
}

// Round 3
// 48488.162 us; speedup vs baseline: 1.0493x; 1.0493x over previous
//
#include <hip/hip_runtime.h>
#include <hip/hip_bf16.h>
#include <hip/hip_cooperative_groups.h>

#define B_   64
#define S_   512
#define IN_  512
#define H_   1024
#define OUT_ 512
#define H3_  3072
#define TC_  32          // timesteps per chunk
#define TCL2 5
#define NCHUNK (S_ / TC_)
#define MC_  (B_ * TC_)  // 2048 rows per chunk
#define NROW (B_ * S_)

typedef float f32x4 __attribute__((ext_vector_type(4)));
typedef short bf16x8 __attribute__((ext_vector_type(8)));
typedef unsigned int u32;

__device__ __forceinline__ u32 f2bf_bits(float v) {
  union { __hip_bfloat16 b; unsigned short s; } cv;
  cv.b = __float2bfloat16(v);
  return (u32)cv.s;
}
__device__ __forceinline__ float bfbits2f(u32 bits) {
  union { unsigned short s; __hip_bfloat16 b; } cv;
  cv.s = (unsigned short)bits;
  return __bfloat162float(cv.b);
}

// L2-bypassing (agent-coherent, LLC-served) accessors
__device__ __forceinline__ u32 coh_ld(const u32* p) {
  return __hip_atomic_load(p, __ATOMIC_RELAXED, __HIP_MEMORY_SCOPE_AGENT);
}
__device__ __forceinline__ void coh_st(u32* p, u32 v) {
  __hip_atomic_store(p, v, __ATOMIC_RELAXED, __HIP_MEMORY_SCOPE_AGENT);
}
__device__ __forceinline__ bf16x8 load_frag_coh(const u32* p) {
  union { u32 u[4]; bf16x8 v; } x;
#pragma unroll
  for (int i = 0; i < 4; ++i) x.u[i] = coh_ld(p + i);
  return x.v;
}

// lightweight grid barrier: monotone LLC counter, no L2 flush/inv.
// __syncthreads drains each wave's outstanding (coherent) stores first.
__device__ __forceinline__ void gbar(u32* ctr, u32 expected) {
  __syncthreads();
  if (threadIdx.x == 0) {
    __hip_atomic_fetch_add(ctr, 1u, __ATOMIC_RELAXED, __HIP_MEMORY_SCOPE_AGENT);
    while (__hip_atomic_load(ctr, __ATOMIC_RELAXED, __HIP_MEMORY_SCOPE_AGENT) < expected) {
      __builtin_amdgcn_s_sleep(1);
    }
  }
  __syncthreads();
}

// ---------------------------------------------------------------------------
__global__ __launch_bounds__(256) void cast_f32_to_bf16(const float* __restrict__ in,
                                                        __hip_bfloat16* __restrict__ out,
                                                        int n4) {
  int i = blockIdx.x * 256 + threadIdx.x;
  if (i >= n4) return;
  float4 v = ((const float4*)in)[i];
  out[4 * i + 0] = __float2bfloat16(v.x);
  out[4 * i + 1] = __float2bfloat16(v.y);
  out[4 * i + 2] = __float2bfloat16(v.z);
  out[4 * i + 3] = __float2bfloat16(v.w);
}

__global__ __launch_bounds__(256) void gather_cast_x(const float* __restrict__ x,
                                                     __hip_bfloat16* __restrict__ out, int t0) {
  int i = blockIdx.x * 256 + threadIdx.x;
  int e = i * 4;
  int b = e >> 14;
  int rem = e & 16383;
  float4 v = *(const float4*)(x + (size_t)b * (S_ * IN_) + (size_t)t0 * IN_ + rem);
  out[e + 0] = __float2bfloat16(v.x);
  out[e + 1] = __float2bfloat16(v.y);
  out[e + 2] = __float2bfloat16(v.z);
  out[e + 3] = __float2bfloat16(v.w);
}

// ---------------------------------------------------------------------------
// C[M,N](f32) = A[M,K](bf16) @ B[N,K](bf16)^T + bias[N]
// ---------------------------------------------------------------------------
template <bool REMAP>
__global__ __launch_bounds__(256) void gemm_nt_bias(const __hip_bfloat16* __restrict__ A,
                                                    const __hip_bfloat16* __restrict__ Bm,
                                                    const float* __restrict__ bias,
                                                    float* __restrict__ C, int M, int N, int K,
                                                    int t0) {
  const int lane = threadIdx.x & 63;
  const int w = threadIdx.x >> 6;
  const int wr = w >> 1, wc = w & 1;
  const int row0 = blockIdx.y * 128 + wr * 64;
  const int col0 = blockIdx.x * 128 + wc * 64;
  const int kl = (lane >> 4) * 8;
  const int m16 = lane & 15;
  f32x4 acc[4][4] = {};
  for (int k0 = 0; k0 < K; k0 += 32) {
    bf16x8 a[4], b[4];
#pragma unroll
    for (int i = 0; i < 4; ++i)
      a[i] = *(const bf16x8*)(A + (size_t)(row0 + i * 16 + m16) * K + k0 + kl);
#pragma unroll
    for (int j = 0; j < 4; ++j)
      b[j] = *(const bf16x8*)(Bm + (size_t)(col0 + j * 16 + m16) * K + k0 + kl);
#pragma unroll
    for (int i = 0; i < 4; ++i)
#pragma unroll
      for (int j = 0; j < 4; ++j)
        acc[i][j] = __builtin_amdgcn_mfma_f32_16x16x32_bf16(a[i], b[j], acc[i][j], 0, 0, 0);
  }
  const int rsub = (lane >> 4) * 4;
#pragma unroll
  for (int i = 0; i < 4; ++i) {
    int row = row0 + i * 16 + rsub;
#pragma unroll
    for (int j = 0; j < 4; ++j) {
      int col = col0 + j * 16 + m16;
      float bv = bias[col];
#pragma unroll
      for (int r = 0; r < 4; ++r) {
        int rr = row + r;
        int crow = REMAP ? ((rr >> TCL2) * S_ + t0 + (rr & (TC_ - 1))) : rr;
        C[(size_t)crow * N + col] = acc[i][j][r] + bv;
      }
    }
  }
}

// ---------------------------------------------------------------------------
// GRU scan, custom-barrier cooperative version. 128 blocks x 256 threads.
// h_pairs/rh_pairs: bf16 pairs in u32, [64 rows][512], agent-coherent path.
// h_f32: [64][1024], block-local columns (block bx owns cols bx*16..+15).
// z: LDS (writer block == reader block).
// ---------------------------------------------------------------------------
__global__ __launch_bounds__(256) void gru_scan_chunk(
    const float* __restrict__ xp, const float* __restrict__ h0, int layer, int t0,
    const __hip_bfloat16* __restrict__ Wh, float* __restrict__ h_f32,
    u32* __restrict__ h_pairs, u32* __restrict__ rh_pairs,
    __hip_bfloat16* __restrict__ y, float* __restrict__ hid_out,
    u32* __restrict__ ctr, u32 ep0) {
  const int tid = threadIdx.x;
  const int lane = tid & 63;
  const int w = tid >> 6;
  const int bx = blockIdx.x;
  const int kl = (lane >> 4) * 8;
  const int m16 = lane & 15;
  const int row0 = w * 16;
  const int arow = row0 + m16;
  const int rsub = (lane >> 4) * 4;

  __shared__ float z_lds[64][16];

  u32 bk = ep0;

  if (t0 == 0 && bx < 64) {  // init h: block bx owns cols bx*16..+15
    for (int i = tid; i < 64 * 16; i += 256) {
      int row = i >> 4;
      int col = bx * 16 + (i & 15);
      float v = h0[((size_t)row * 2 + layer) * H_ + col];
      h_f32[row * H_ + col] = v;
      // store bf16 pair halves: do a full-pair read-modify would race; instead
      // each even col's thread builds the pair from the two h0 values.
      if ((col & 1) == 0) {
        float v1 = h0[((size_t)row * 2 + layer) * H_ + col + 1];
        coh_st(h_pairs + row * 512 + (col >> 1), f2bf_bits(v) | (f2bf_bits(v1) << 16));
      }
    }
  }
  ++bk;
  gbar(ctr, bk * 128u);

  for (int t = 0; t < TC_; ++t) {
    // ---- phase A: z (bx<64) and r->rh (bx>=64) ----
    {
      const int c = bx * 16 + m16;  // 0..2047
      f32x4 acc0 = {}, acc1 = {};
      const u32* Ap = h_pairs + (size_t)arow * 512;
      const __hip_bfloat16* Bb = Wh + (size_t)c * H_;
#pragma unroll
      for (int k0 = 0; k0 < H_; k0 += 64) {
        bf16x8 a0 = load_frag_coh(Ap + ((k0 + kl) >> 1));
        bf16x8 b0 = *(const bf16x8*)(Bb + k0 + kl);
        bf16x8 a1 = load_frag_coh(Ap + ((k0 + 32 + kl) >> 1));
        bf16x8 b1 = *(const bf16x8*)(Bb + k0 + 32 + kl);
        acc0 = __builtin_amdgcn_mfma_f32_16x16x32_bf16(a0, b0, acc0, 0, 0, 0);
        acc1 = __builtin_amdgcn_mfma_f32_16x16x32_bf16(a1, b1, acc1, 0, 0, 0);
      }
      if (bx < 64) {
#pragma unroll
        for (int j = 0; j < 4; ++j) {
          int row = row0 + rsub + j;
          float pre = acc0[j] + acc1[j] + xp[((size_t)(row * TC_ + t)) * H3_ + c];
          z_lds[row][m16] = 1.f / (1.f + expf(-pre));
        }
      } else {
        const int hc = c - H_;  // 0..1023
#pragma unroll
        for (int j = 0; j < 4; ++j) {
          int row = row0 + rsub + j;
          float pre = acc0[j] + acc1[j] + xp[((size_t)(row * TC_ + t)) * H3_ + c];
          float s = 1.f / (1.f + expf(-pre));
          u32 hp = coh_ld(h_pairs + row * 512 + (hc >> 1));
          float hv = bfbits2f((hc & 1) ? (hp >> 16) : hp);
          u32 bits = f2bf_bits(s * hv);
          u32 pair = bits | (((u32)__shfl_down((int)bits, 1)) << 16);
          if ((m16 & 1) == 0) coh_st(rh_pairs + row * 512 + (hc >> 1), pair);
        }
      }
    }
    ++bk;
    gbar(ctr, bk * 128u);

    // ---- phase B: g + h update (bx<64) ----
    if (bx < 64) {
      const int c = bx * 16 + m16;  // 0..1023
      f32x4 acc0 = {}, acc1 = {};
      const u32* Ap = rh_pairs + (size_t)arow * 512;
      const __hip_bfloat16* Bb = Wh + (size_t)(2 * H_ + c) * H_;
#pragma unroll
      for (int k0 = 0; k0 < H_; k0 += 64) {
        bf16x8 a0 = load_frag_coh(Ap + ((k0 + kl) >> 1));
        bf16x8 b0 = *(const bf16x8*)(Bb + k0 + kl);
        bf16x8 a1 = load_frag_coh(Ap + ((k0 + 32 + kl) >> 1));
        bf16x8 b1 = *(const bf16x8*)(Bb + k0 + 32 + kl);
        acc0 = __builtin_amdgcn_mfma_f32_16x16x32_bf16(a0, b0, acc0, 0, 0, 0);
        acc1 = __builtin_amdgcn_mfma_f32_16x16x32_bf16(a1, b1, acc1, 0, 0, 0);
      }
#pragma unroll
      for (int j = 0; j < 4; ++j) {
        int row = row0 + rsub + j;
        float pre = acc0[j] + acc1[j] + xp[((size_t)(row * TC_ + t)) * H3_ + 2 * H_ + c];
        float gg = tanhf(pre);
        int idx = row * H_ + c;
        float zz = z_lds[row][m16];
        float hn = zz * h_f32[idx] + (1.f - zz) * gg;
        h_f32[idx] = hn;
        u32 bits = f2bf_bits(hn);
        u32 pair = bits | (((u32)__shfl_down((int)bits, 1)) << 16);
        if ((m16 & 1) == 0) coh_st(h_pairs + row * 512 + (c >> 1), pair);
        y[((size_t)(row * TC_ + t)) * H_ + c] = __float2bfloat16(hn);
      }
    }
    ++bk;
    gbar(ctr, bk * 128u);
  }

  if (t0 + TC_ == S_ && bx < 64) {  // final hidden state (own cols)
    for (int i = tid; i < 64 * 16; i += 256) {
      int row = i >> 4;
      int col = bx * 16 + (i & 15);
      hid_out[((size_t)row * 2 + layer) * H_ + col] = h_f32[row * H_ + col];
    }
  }
}

// ---------------------------------------------------------------------------
extern "C" void kernel_launch(void* const* d_in, const int* in_sizes, int n_in,
                              void* d_out, int out_size, void* d_ws, size_t ws_size,
                              hipStream_t stream) {
  const float* x   = (const float*)d_in[0];
  const float* h0  = (const float*)d_in[1];
  const float* Wx0 = (const float*)d_in[2];
  const float* Wh0 = (const float*)d_in[3];
  const float* bh0 = (const float*)d_in[4];
  const float* Wx1 = (const float*)d_in[5];
  const float* Wh1 = (const float*)d_in[6];
  const float* bh1 = (const float*)d_in[7];
  const float* Why = (const float*)d_in[8];
  const float* by  = (const float*)d_in[9];
  float* out = (float*)d_out;
  float* hid_out = out + (size_t)NROW * OUT_;

  char* ws = (char*)d_ws;
  size_t off = 0;
  auto alloc = [&](size_t bytes) {
    char* p = ws + off;
    off += (bytes + 255) & ~(size_t)255;
    return p;
  };
  __hip_bfloat16* wx0b = (__hip_bfloat16*)alloc((size_t)H3_ * IN_ * 2);
  __hip_bfloat16* wh0b = (__hip_bfloat16*)alloc((size_t)H3_ * H_ * 2);
  __hip_bfloat16* wx1b = (__hip_bfloat16*)alloc((size_t)H3_ * H_ * 2);
  __hip_bfloat16* wh1b = (__hip_bfloat16*)alloc((size_t)H3_ * H_ * 2);
  __hip_bfloat16* whyb = (__hip_bfloat16*)alloc((size_t)OUT_ * H_ * 2);
  float* h_f32_0 = (float*)alloc((size_t)B_ * H_ * 4);
  float* h_f32_1 = (float*)alloc((size_t)B_ * H_ * 4);
  u32* h_pairs_0 = (u32*)alloc((size_t)B_ * 512 * 4);
  u32* h_pairs_1 = (u32*)alloc((size_t)B_ * 512 * 4);
  u32* rh_pairs  = (u32*)alloc((size_t)B_ * 512 * 4);
  __hip_bfloat16* x_bfc = (__hip_bfloat16*)alloc((size_t)MC_ * IN_ * 2);
  __hip_bfloat16* y_c   = (__hip_bfloat16*)alloc((size_t)MC_ * H_ * 2);
  float* xp_c           = (float*)alloc((size_t)MC_ * H3_ * 4);
  u32* ctr              = (u32*)alloc(256);
  (void)ws_size;

  hipMemsetAsync(ctr, 0, 4, stream);

  auto cast = [&](const float* in, __hip_bfloat16* o, size_t n) {
    cast_f32_to_bf16<<<dim3((unsigned)((n / 4 + 255) / 256)), dim3(256), 0, stream>>>(in, o,
                                                                                     (int)(n / 4));
  };
  cast(Wx0, wx0b, (size_t)H3_ * IN_);
  cast(Wh0, wh0b, (size_t)H3_ * H_);
  cast(Wx1, wx1b, (size_t)H3_ * H_);
  cast(Wh1, wh1b, (size_t)H3_ * H_);
  cast(Why, whyb, (size_t)OUT_ * H_);

  const u32 EPK = 1 + 2 * TC_;  // barriers per scan kernel

  for (int c = 0; c < NCHUNK; ++c) {
    int t0 = c * TC_;
    gather_cast_x<<<dim3(MC_ * IN_ / 4 / 256), dim3(256), 0, stream>>>(x, x_bfc, t0);
    gemm_nt_bias<false><<<dim3(H3_ / 128, MC_ / 128), dim3(256), 0, stream>>>(
        x_bfc, wx0b, bh0, xp_c, MC_, H3_, IN_, 0);
    {
      int layer = 0;
      u32 ep0 = (u32)(2 * c + 0) * EPK;
      void* args[] = {(void*)&xp_c, (void*)&h0,        (void*)&layer,    (void*)&t0,
                      (void*)&wh0b, (void*)&h_f32_0,   (void*)&h_pairs_0,
                      (void*)&rh_pairs, (void*)&y_c,   (void*)&hid_out,  (void*)&ctr,
                      (void*)&ep0};
      hipLaunchCooperativeKernel((void*)gru_scan_chunk, dim3(128), dim3(256), args, 0, stream);
    }
    gemm_nt_bias<false><<<dim3(H3_ / 128, MC_ / 128), dim3(256), 0, stream>>>(
        y_c, wx1b, bh1, xp_c, MC_, H3_, H_, 0);
    {
      int layer = 1;
      u32 ep0 = (u32)(2 * c + 1) * EPK;
      void* args[] = {(void*)&xp_c, (void*)&h0,        (void*)&layer,    (void*)&t0,
                      (void*)&wh1b, (void*)&h_f32_1,   (void*)&h_pairs_1,
                      (void*)&rh_pairs, (void*)&y_c,   (void*)&hid_out,  (void*)&ctr,
                      (void*)&ep0};
      hipLaunchCooperativeKernel((void*)gru_scan_chunk, dim3(128), dim3(256), args, 0, stream);
    }
    gemm_nt_bias<true><<<dim3(OUT_ / 128, MC_ / 128), dim3(256), 0, stream>>>(
        y_c, whyb, by, out, MC_, OUT_, H_, t0);
  }
}

// Round 4
// 22052.641 us; speedup vs baseline: 2.3071x; 2.1987x over previous
//
#include <hip/hip_runtime.h>
#include <hip/hip_bf16.h>

#define B_   64
#define S_   512
#define IN_  512
#define H_   1024
#define OUT_ 512
#define H3_  3072
#define TC_  32          // timesteps per chunk
#define TCL2 5
#define NCHUNK (S_ / TC_)
#define MC_  (B_ * TC_)  // 2048 rows per chunk
#define NROW (B_ * S_)
#define NBLK 64
#define NTHR 512
#define SMEM_BYTES (131072 + 4096 + 4096)

typedef float f32x4 __attribute__((ext_vector_type(4)));
typedef short bf16x8 __attribute__((ext_vector_type(8)));
typedef unsigned int u32;
typedef u32 u32x4 __attribute__((ext_vector_type(4)));

__device__ __forceinline__ u32 f2bf_bits(float v) {
  union { __hip_bfloat16 b; unsigned short s; } cv;
  cv.b = __float2bfloat16(v);
  return (u32)cv.s;
}

// agent-coherent (LLC-served) scalar ops for scattered epilogue stores / ctr
__device__ __forceinline__ void coh_st(u32* p, u32 v) {
  __hip_atomic_store(p, v, __ATOMIC_RELAXED, __HIP_MEMORY_SCOPE_AGENT);
}

// lightweight grid barrier: monotone LLC counter, no cache maintenance.
__device__ __forceinline__ void gbar(u32* ctr, u32 expected) {
  __syncthreads();  // drains each wave's vmcnt -> coherent stores visible
  if (threadIdx.x == 0) {
    __hip_atomic_fetch_add(ctr, 1u, __ATOMIC_RELAXED, __HIP_MEMORY_SCOPE_AGENT);
    while (__hip_atomic_load(ctr, __ATOMIC_RELAXED, __HIP_MEMORY_SCOPE_AGENT) < expected) {
      __builtin_amdgcn_s_sleep(1);
    }
  }
  __syncthreads();
}

// stage 128KB pair buffer [64 rows][512 u32] into LDS, swizzled, coalesced,
// L2-bypassing (sc0 sc1) so cross-XCD writes are observed.
__device__ __forceinline__ void stage_pairs(const u32* __restrict__ src, char* stage, int tid) {
#pragma unroll
  for (int half = 0; half < 2; ++half) {
    u32x4 v[8];
#pragma unroll
    for (int i = 0; i < 8; ++i) {
      int c4 = tid + (half * 8 + i) * NTHR;  // x4-chunk index, 8192 total
      asm volatile("global_load_dwordx4 %0, %1, off sc0 sc1"
                   : "=v"(v[i])
                   : "v"(src + (size_t)c4 * 4));
    }
    asm volatile("s_waitcnt vmcnt(0)" ::: "memory");
#pragma unroll
    for (int i = 0; i < 8; ++i) {
      int c4 = tid + (half * 8 + i) * NTHR;
      int row = c4 >> 7;                       // 128 x4-chunks per row
      int off = (c4 & 127) * 16;               // byte offset within row
      int byte = row * 2048 + (off ^ ((row & 7) << 4));
      *(u32x4*)(stage + byte) = v[i];
    }
  }
}

// ---------------------------------------------------------------------------
__global__ __launch_bounds__(256) void cast_f32_to_bf16(const float* __restrict__ in,
                                                        __hip_bfloat16* __restrict__ out,
                                                        int n4) {
  int i = blockIdx.x * 256 + threadIdx.x;
  if (i >= n4) return;
  float4 v = ((const float4*)in)[i];
  out[4 * i + 0] = __float2bfloat16(v.x);
  out[4 * i + 1] = __float2bfloat16(v.y);
  out[4 * i + 2] = __float2bfloat16(v.z);
  out[4 * i + 3] = __float2bfloat16(v.w);
}

__global__ __launch_bounds__(256) void gather_cast_x(const float* __restrict__ x,
                                                     __hip_bfloat16* __restrict__ out, int t0) {
  int i = blockIdx.x * 256 + threadIdx.x;
  int e = i * 4;
  int b = e >> 14;
  int rem = e & 16383;
  float4 v = *(const float4*)(x + (size_t)b * (S_ * IN_) + (size_t)t0 * IN_ + rem);
  out[e + 0] = __float2bfloat16(v.x);
  out[e + 1] = __float2bfloat16(v.y);
  out[e + 2] = __float2bfloat16(v.z);
  out[e + 3] = __float2bfloat16(v.w);
}

// ---------------------------------------------------------------------------
// C[M,N](f32) = A[M,K](bf16) @ B[N,K](bf16)^T + bias[N]
// ---------------------------------------------------------------------------
template <bool REMAP>
__global__ __launch_bounds__(256) void gemm_nt_bias(const __hip_bfloat16* __restrict__ A,
                                                    const __hip_bfloat16* __restrict__ Bm,
                                                    const float* __restrict__ bias,
                                                    float* __restrict__ C, int M, int N, int K,
                                                    int t0) {
  const int lane = threadIdx.x & 63;
  const int w = threadIdx.x >> 6;
  const int wr = w >> 1, wc = w & 1;
  const int row0 = blockIdx.y * 128 + wr * 64;
  const int col0 = blockIdx.x * 128 + wc * 64;
  const int kl = (lane >> 4) * 8;
  const int m16 = lane & 15;
  f32x4 acc[4][4] = {};
  for (int k0 = 0; k0 < K; k0 += 32) {
    bf16x8 a[4], b[4];
#pragma unroll
    for (int i = 0; i < 4; ++i)
      a[i] = *(const bf16x8*)(A + (size_t)(row0 + i * 16 + m16) * K + k0 + kl);
#pragma unroll
    for (int j = 0; j < 4; ++j)
      b[j] = *(const bf16x8*)(Bm + (size_t)(col0 + j * 16 + m16) * K + k0 + kl);
#pragma unroll
    for (int i = 0; i < 4; ++i)
#pragma unroll
      for (int j = 0; j < 4; ++j)
        acc[i][j] = __builtin_amdgcn_mfma_f32_16x16x32_bf16(a[i], b[j], acc[i][j], 0, 0, 0);
  }
  const int rsub = (lane >> 4) * 4;
#pragma unroll
  for (int i = 0; i < 4; ++i) {
    int row = row0 + i * 16 + rsub;
#pragma unroll
    for (int j = 0; j < 4; ++j) {
      int col = col0 + j * 16 + m16;
      float bv = bias[col];
#pragma unroll
      for (int r = 0; r < 4; ++r) {
        int rr = row + r;
        int crow = REMAP ? ((rr >> TCL2) * S_ + t0 + (rr & (TC_ - 1))) : rr;
        C[(size_t)crow * N + col] = acc[i][j][r] + bv;
      }
    }
  }
}

// ---------------------------------------------------------------------------
// GRU scan: 64 blocks x 512 thr. Block b owns cols [16b,16b+16) (z,g,h) and
// r-cols [H+16b, H+16b+16). Per phase, full h (or rh) staged into LDS via
// coalesced coherent loads; z/h block-local in LDS.
// ---------------------------------------------------------------------------
__global__ __launch_bounds__(NTHR) void gru_scan_chunk(
    const float* __restrict__ xp, const float* __restrict__ h0, int layer, int t0,
    const __hip_bfloat16* __restrict__ Wh, float* __restrict__ h_f32,
    u32* __restrict__ h_pairs, u32* __restrict__ rh_pairs,
    __hip_bfloat16* __restrict__ y, float* __restrict__ hid_out,
    u32* __restrict__ ctr, u32 ep0) {
  extern __shared__ char smem_raw[];
  char* stage = smem_raw;                       // 128 KB swizzled bf16 [64][1024]
  float* h_own = (float*)(smem_raw + 131072);   // [64][16]
  float* z_own = h_own + 64 * 16;               // [64][16]

  const int tid = threadIdx.x;
  const int lane = tid & 63;
  const int w = tid >> 6;
  const int b = blockIdx.x;
  const int m16 = lane & 15;
  const int kl = (lane >> 4) * 8;
  const int rsub = (lane >> 4) * 4;

  u32 bk = ep0;

  {  // init / reload h_own; (t0==0) also publish h_pairs
    int row = tid >> 3, pi = tid & 7;
    int col = b * 16 + pi * 2;
    float v0, v1;
    if (t0 == 0) {
      v0 = h0[((size_t)row * 2 + layer) * H_ + col];
      v1 = h0[((size_t)row * 2 + layer) * H_ + col + 1];
      coh_st(h_pairs + row * 512 + (col >> 1), f2bf_bits(v0) | (f2bf_bits(v1) << 16));
    } else {
      v0 = h_f32[row * H_ + col];      // prev dispatch flushed at kernel end
      v1 = h_f32[row * H_ + col + 1];  // h_pairs persists from prev dispatch
    }
    h_own[row * 16 + pi * 2] = v0;
    h_own[row * 16 + pi * 2 + 1] = v1;
  }
  ++bk;
  gbar(ctr, bk * NBLK);

  for (int t = 0; t < TC_; ++t) {
    // ================= phase A: z (even waves) / r->rh (odd waves) ========
    const int colA = b * 16 + m16 + ((w & 1) ? H_ : 0);
    const int row0 = (w >> 1) * 16;
    float xpv[4];
#pragma unroll
    for (int j = 0; j < 4; ++j) {
      int row = row0 + rsub + j;
      xpv[j] = xp[((size_t)(row * TC_ + t)) * H3_ + colA];
    }
    stage_pairs(h_pairs, stage, tid);
    __syncthreads();
    {
      f32x4 acc0 = {}, acc1 = {};
      const __hip_bfloat16* Bb = Wh + (size_t)colA * H_;
      const int ar = row0 + m16;
      const int abase = ar * 2048;
      const int swz = (ar & 7) << 4;
#pragma unroll
      for (int k0 = 0; k0 < H_; k0 += 64) {
        bf16x8 a0 = *(const bf16x8*)(stage + abase + (((k0 + kl) * 2) ^ swz));
        bf16x8 a1 = *(const bf16x8*)(stage + abase + (((k0 + 32 + kl) * 2) ^ swz));
        bf16x8 b0 = *(const bf16x8*)(Bb + k0 + kl);
        bf16x8 b1 = *(const bf16x8*)(Bb + k0 + 32 + kl);
        acc0 = __builtin_amdgcn_mfma_f32_16x16x32_bf16(a0, b0, acc0, 0, 0, 0);
        acc1 = __builtin_amdgcn_mfma_f32_16x16x32_bf16(a1, b1, acc1, 0, 0, 0);
      }
      if ((w & 1) == 0) {  // z columns (block-local)
#pragma unroll
        for (int j = 0; j < 4; ++j) {
          int row = row0 + rsub + j;
          float pre = acc0[j] + acc1[j] + xpv[j];
          z_own[row * 16 + m16] = 1.f / (1.f + expf(-pre));
        }
      } else {  // r columns -> rh exchange
#pragma unroll
        for (int j = 0; j < 4; ++j) {
          int row = row0 + rsub + j;
          float pre = acc0[j] + acc1[j] + xpv[j];
          float s = 1.f / (1.f + expf(-pre));
          float rh = s * h_own[row * 16 + m16];
          u32 bits = f2bf_bits(rh);
          u32 pair = bits | (((u32)__shfl_down((int)bits, 1)) << 16);
          if ((m16 & 1) == 0) coh_st(rh_pairs + row * 512 + ((b * 16 + m16) >> 1), pair);
        }
      }
    }
    ++bk;
    gbar(ctr, bk * NBLK);

    // ================= phase B: g + h update (waves 0..3) =================
    float xpg[4];
    if (w < 4) {
#pragma unroll
      for (int j = 0; j < 4; ++j) {
        int row = w * 16 + rsub + j;
        xpg[j] = xp[((size_t)(row * TC_ + t)) * H3_ + 2 * H_ + b * 16 + m16];
      }
    }
    stage_pairs(rh_pairs, stage, tid);
    __syncthreads();
    if (w < 4) {
      const int row0b = w * 16;
      const int cb = b * 16 + m16;
      f32x4 acc0 = {}, acc1 = {};
      const __hip_bfloat16* Bb = Wh + (size_t)(2 * H_ + cb) * H_;
      const int ar = row0b + m16;
      const int abase = ar * 2048;
      const int swz = (ar & 7) << 4;
#pragma unroll
      for (int k0 = 0; k0 < H_; k0 += 64) {
        bf16x8 a0 = *(const bf16x8*)(stage + abase + (((k0 + kl) * 2) ^ swz));
        bf16x8 a1 = *(const bf16x8*)(stage + abase + (((k0 + 32 + kl) * 2) ^ swz));
        bf16x8 b0 = *(const bf16x8*)(Bb + k0 + kl);
        bf16x8 b1 = *(const bf16x8*)(Bb + k0 + 32 + kl);
        acc0 = __builtin_amdgcn_mfma_f32_16x16x32_bf16(a0, b0, acc0, 0, 0, 0);
        acc1 = __builtin_amdgcn_mfma_f32_16x16x32_bf16(a1, b1, acc1, 0, 0, 0);
      }
#pragma unroll
      for (int j = 0; j < 4; ++j) {
        int row = row0b + rsub + j;
        float pre = acc0[j] + acc1[j] + xpg[j];
        float gg = tanhf(pre);
        float zz = z_own[row * 16 + m16];
        float hv = h_own[row * 16 + m16];
        float hn = zz * hv + (1.f - zz) * gg;
        h_own[row * 16 + m16] = hn;
        u32 bits = f2bf_bits(hn);
        u32 pair = bits | (((u32)__shfl_down((int)bits, 1)) << 16);
        if ((m16 & 1) == 0) coh_st(h_pairs + row * 512 + ((b * 16 + m16) >> 1), pair);
        y[((size_t)(row * TC_ + t)) * H_ + cb] = __float2bfloat16(hn);
      }
    }
    ++bk;
    gbar(ctr, bk * NBLK);
  }

  {  // persist h_own (last gbar's __syncthreads makes h_own coherent)
    int row = tid >> 3, pi = tid & 7;
    int col = b * 16 + pi * 2;
    float v0 = h_own[row * 16 + pi * 2];
    float v1 = h_own[row * 16 + pi * 2 + 1];
    h_f32[row * H_ + col] = v0;
    h_f32[row * H_ + col + 1] = v1;
    if (t0 + TC_ == S_) {
      hid_out[((size_t)row * 2 + layer) * H_ + col] = v0;
      hid_out[((size_t)row * 2 + layer) * H_ + col + 1] = v1;
    }
  }
}

// ---------------------------------------------------------------------------
extern "C" void kernel_launch(void* const* d_in, const int* in_sizes, int n_in,
                              void* d_out, int out_size, void* d_ws, size_t ws_size,
                              hipStream_t stream) {
  const float* x   = (const float*)d_in[0];
  const float* h0  = (const float*)d_in[1];
  const float* Wx0 = (const float*)d_in[2];
  const float* Wh0 = (const float*)d_in[3];
  const float* bh0 = (const float*)d_in[4];
  const float* Wx1 = (const float*)d_in[5];
  const float* Wh1 = (const float*)d_in[6];
  const float* bh1 = (const float*)d_in[7];
  const float* Why = (const float*)d_in[8];
  const float* by  = (const float*)d_in[9];
  float* out = (float*)d_out;
  float* hid_out = out + (size_t)NROW * OUT_;

  hipFuncSetAttribute((const void*)gru_scan_chunk,
                      hipFuncAttributeMaxDynamicSharedMemorySize, SMEM_BYTES);

  char* ws = (char*)d_ws;
  size_t off = 0;
  auto alloc = [&](size_t bytes) {
    char* p = ws + off;
    off += (bytes + 255) & ~(size_t)255;
    return p;
  };
  __hip_bfloat16* wx0b = (__hip_bfloat16*)alloc((size_t)H3_ * IN_ * 2);
  __hip_bfloat16* wh0b = (__hip_bfloat16*)alloc((size_t)H3_ * H_ * 2);
  __hip_bfloat16* wx1b = (__hip_bfloat16*)alloc((size_t)H3_ * H_ * 2);
  __hip_bfloat16* wh1b = (__hip_bfloat16*)alloc((size_t)H3_ * H_ * 2);
  __hip_bfloat16* whyb = (__hip_bfloat16*)alloc((size_t)OUT_ * H_ * 2);
  float* h_f32_0 = (float*)alloc((size_t)B_ * H_ * 4);
  float* h_f32_1 = (float*)alloc((size_t)B_ * H_ * 4);
  u32* h_pairs_0 = (u32*)alloc((size_t)B_ * 512 * 4);
  u32* h_pairs_1 = (u32*)alloc((size_t)B_ * 512 * 4);
  u32* rh_pairs  = (u32*)alloc((size_t)B_ * 512 * 4);
  __hip_bfloat16* x_bfc = (__hip_bfloat16*)alloc((size_t)MC_ * IN_ * 2);
  __hip_bfloat16* y_c   = (__hip_bfloat16*)alloc((size_t)MC_ * H_ * 2);
  float* xp_c           = (float*)alloc((size_t)MC_ * H3_ * 4);
  u32* ctr              = (u32*)alloc(256);
  (void)ws_size;

  hipMemsetAsync(ctr, 0, 4, stream);

  auto cast = [&](const float* in, __hip_bfloat16* o, size_t n) {
    cast_f32_to_bf16<<<dim3((unsigned)((n / 4 + 255) / 256)), dim3(256), 0, stream>>>(in, o,
                                                                                     (int)(n / 4));
  };
  cast(Wx0, wx0b, (size_t)H3_ * IN_);
  cast(Wh0, wh0b, (size_t)H3_ * H_);
  cast(Wx1, wx1b, (size_t)H3_ * H_);
  cast(Wh1, wh1b, (size_t)H3_ * H_);
  cast(Why, whyb, (size_t)OUT_ * H_);

  const u32 EPK = 1 + 2 * TC_;  // barriers per scan dispatch

  for (int c = 0; c < NCHUNK; ++c) {
    int t0 = c * TC_;
    gather_cast_x<<<dim3(MC_ * IN_ / 4 / 256), dim3(256), 0, stream>>>(x, x_bfc, t0);
    gemm_nt_bias<false><<<dim3(H3_ / 128, MC_ / 128), dim3(256), 0, stream>>>(
        x_bfc, wx0b, bh0, xp_c, MC_, H3_, IN_, 0);
    {
      int layer = 0;
      u32 ep0 = (u32)(2 * c + 0) * EPK;
      void* args[] = {(void*)&xp_c,     (void*)&h0,      (void*)&layer,     (void*)&t0,
                      (void*)&wh0b,     (void*)&h_f32_0, (void*)&h_pairs_0,
                      (void*)&rh_pairs, (void*)&y_c,     (void*)&hid_out,   (void*)&ctr,
                      (void*)&ep0};
      hipLaunchCooperativeKernel((void*)gru_scan_chunk, dim3(NBLK), dim3(NTHR), args, SMEM_BYTES,
                                 stream);
    }
    gemm_nt_bias<false><<<dim3(H3_ / 128, MC_ / 128), dim3(256), 0, stream>>>(
        y_c, wx1b, bh1, xp_c, MC_, H3_, H_, 0);
    {
      int layer = 1;
      u32 ep0 = (u32)(2 * c + 1) * EPK;
      void* args[] = {(void*)&xp_c,     (void*)&h0,      (void*)&layer,     (void*)&t0,
                      (void*)&wh1b,     (void*)&h_f32_1, (void*)&h_pairs_1,
                      (void*)&rh_pairs, (void*)&y_c,     (void*)&hid_out,   (void*)&ctr,
                      (void*)&ep0};
      hipLaunchCooperativeKernel((void*)gru_scan_chunk, dim3(NBLK), dim3(NTHR), args, SMEM_BYTES,
                                 stream);
    }
    gemm_nt_bias<true><<<dim3(OUT_ / 128, MC_ / 128), dim3(256), 0, stream>>>(
        y_c, whyb, by, out, MC_, OUT_, H_, t0);
  }
}

// Round 6
// 18846.835 us; speedup vs baseline: 2.6996x; 1.1701x over previous
//
#include <hip/hip_runtime.h>
#include <hip/hip_bf16.h>

#define B_   64
#define S_   512
#define IN_  512
#define H_   1024
#define OUT_ 512
#define H3_  3072
#define TC_  32          // timesteps per chunk
#define TCL2 5
#define NCHUNK (S_ / TC_)
#define MC_  (B_ * TC_)  // 2048 rows per chunk
#define NROW (B_ * S_)

// scan decomposition: 256 blocks = 4 row-groups x 64 col-groups, 128 thr each
#define NBLK 256
#define NTHR 128
#define STAGE_OFF 0        // 16 rows x 2048 B = 32768
#define HOWN_OFF  32768    // 16x17 f32 = 1088 (pad to 1152)
#define ZOWN_OFF  33920    // 16x17 f32 = 1088
#define SMEM_BYTES 35072

typedef float f32x4 __attribute__((ext_vector_type(4)));
typedef short bf16x8 __attribute__((ext_vector_type(8)));
typedef unsigned int u32;
typedef u32 u32x4 __attribute__((ext_vector_type(4)));

__device__ __forceinline__ u32 f2bf_bits(float v) {
  union { __hip_bfloat16 b; unsigned short s; } cv;
  cv.b = __float2bfloat16(v);
  return (u32)cv.s;
}

// agent-coherent (LLC-served) store for cross-XCD exchange
__device__ __forceinline__ void coh_st(u32* p, u32 v) {
  __hip_atomic_store(p, v, __ATOMIC_RELAXED, __HIP_MEMORY_SCOPE_AGENT);
}

// lightweight grid barrier: monotone LLC counter, no cache maintenance.
__device__ __forceinline__ void gbar(u32* ctr, u32 expected) {
  __syncthreads();  // compiler emits vmcnt(0) drain -> coherent stores visible
  if (threadIdx.x == 0) {
    __hip_atomic_fetch_add(ctr, 1u, __ATOMIC_RELAXED, __HIP_MEMORY_SCOPE_AGENT);
    while (__hip_atomic_load(ctr, __ATOMIC_RELAXED, __HIP_MEMORY_SCOPE_AGENT) < expected) {
      __builtin_amdgcn_s_sleep(1);
    }
  }
  __syncthreads();
}

// stage 32KB pair slab [16 rows][512 u32] into LDS (XOR-swizzled), coalesced,
// LLC-coherent loads (sc0 sc1) so cross-XCD writes are observed.
__device__ __forceinline__ void stage16(const u32* __restrict__ src, char* stage, int tid) {
  u32x4 v[16];
#pragma unroll
  for (int i = 0; i < 16; ++i) {
    int c4 = tid + i * NTHR;  // 2048 x4-chunks total
    asm volatile("global_load_dwordx4 %0, %1, off sc0 sc1"
                 : "=v"(v[i])
                 : "v"(src + (size_t)c4 * 4));
  }
  asm volatile("s_waitcnt vmcnt(0)" ::: "memory");
#pragma unroll
  for (int i = 0; i < 16; ++i) {
    int c4 = tid + i * NTHR;
    int row = c4 >> 7;          // 128 x4-chunks per row
    int off = (c4 & 127) * 16;  // byte offset within row
    *(u32x4*)(stage + row * 2048 + (off ^ ((row & 7) << 4))) = v[i];
  }
}

// ---------------------------------------------------------------------------
__global__ __launch_bounds__(256) void cast_f32_to_bf16(const float* __restrict__ in,
                                                        __hip_bfloat16* __restrict__ out,
                                                        int n4) {
  int i = blockIdx.x * 256 + threadIdx.x;
  if (i >= n4) return;
  float4 v = ((const float4*)in)[i];
  out[4 * i + 0] = __float2bfloat16(v.x);
  out[4 * i + 1] = __float2bfloat16(v.y);
  out[4 * i + 2] = __float2bfloat16(v.z);
  out[4 * i + 3] = __float2bfloat16(v.w);
}

__global__ __launch_bounds__(256) void gather_cast_x(const float* __restrict__ x,
                                                     __hip_bfloat16* __restrict__ out, int t0) {
  int i = blockIdx.x * 256 + threadIdx.x;
  int e = i * 4;
  int b = e >> 14;
  int rem = e & 16383;
  float4 v = *(const float4*)(x + (size_t)b * (S_ * IN_) + (size_t)t0 * IN_ + rem);
  out[e + 0] = __float2bfloat16(v.x);
  out[e + 1] = __float2bfloat16(v.y);
  out[e + 2] = __float2bfloat16(v.z);
  out[e + 3] = __float2bfloat16(v.w);
}

// ---------------------------------------------------------------------------
// C[M,N](f32) = A[M,K](bf16) @ B[N,K](bf16)^T + bias[N]
// ---------------------------------------------------------------------------
template <bool REMAP>
__global__ __launch_bounds__(256) void gemm_nt_bias(const __hip_bfloat16* __restrict__ A,
                                                    const __hip_bfloat16* __restrict__ Bm,
                                                    const float* __restrict__ bias,
                                                    float* __restrict__ C, int M, int N, int K,
                                                    int t0) {
  const int lane = threadIdx.x & 63;
  const int w = threadIdx.x >> 6;
  const int wr = w >> 1, wc = w & 1;
  const int row0 = blockIdx.y * 128 + wr * 64;
  const int col0 = blockIdx.x * 128 + wc * 64;
  const int kl = (lane >> 4) * 8;
  const int m16 = lane & 15;
  f32x4 acc[4][4] = {};
  for (int k0 = 0; k0 < K; k0 += 32) {
    bf16x8 a[4], b[4];
#pragma unroll
    for (int i = 0; i < 4; ++i)
      a[i] = *(const bf16x8*)(A + (size_t)(row0 + i * 16 + m16) * K + k0 + kl);
#pragma unroll
    for (int j = 0; j < 4; ++j)
      b[j] = *(const bf16x8*)(Bm + (size_t)(col0 + j * 16 + m16) * K + k0 + kl);
#pragma unroll
    for (int i = 0; i < 4; ++i)
#pragma unroll
      for (int j = 0; j < 4; ++j)
        acc[i][j] = __builtin_amdgcn_mfma_f32_16x16x32_bf16(a[i], b[j], acc[i][j], 0, 0, 0);
  }
  const int rsub = (lane >> 4) * 4;
#pragma unroll
  for (int i = 0; i < 4; ++i) {
    int row = row0 + i * 16 + rsub;
#pragma unroll
    for (int j = 0; j < 4; ++j) {
      int col = col0 + j * 16 + m16;
      float bv = bias[col];
#pragma unroll
      for (int r = 0; r < 4; ++r) {
        int rr = row + r;
        int crow = REMAP ? ((rr >> TCL2) * S_ + t0 + (rr & (TC_ - 1))) : rr;
        C[(size_t)crow * N + col] = acc[i][j][r] + bv;
      }
    }
  }
}

// ---------------------------------------------------------------------------
// GRU scan: 256 blocks (rg=bx>>6 in 0..3, cg=bx&63) x 128 thr (2 waves).
// Block owns 16 batch rows (rg) x 16 cols (cg). Per phase, stages only its
// 16 rows of the h (or rh) exchange (32 KB) via coherent coalesced loads.
// Weights read directly from L2 (round-4-proven pattern).
// Phase A: wave0 -> z (block-local LDS), wave1 -> r, rh published.
// Phase B: wave0 -> g + h update, h published; wave1 stages only.
// ---------------------------------------------------------------------------
__global__ __launch_bounds__(NTHR) void gru_scan_chunk(
    const float* __restrict__ xp, const float* __restrict__ h0, int layer, int t0,
    const __hip_bfloat16* __restrict__ Wh, float* __restrict__ h_f32,
    u32* __restrict__ h_pairs, u32* __restrict__ rh_pairs,
    __hip_bfloat16* __restrict__ y, float* __restrict__ hid_out,
    u32* __restrict__ ctr, u32 ep0) {
  extern __shared__ char smem[];
  char* stage = smem + STAGE_OFF;
  float* h_own = (float*)(smem + HOWN_OFF);  // [16][17]
  float* z_own = (float*)(smem + ZOWN_OFF);  // [16][17]

  const int tid = threadIdx.x;
  const int lane = tid & 63;
  const int w = tid >> 6;
  const int bx = blockIdx.x;
  const int rg = bx >> 6;
  const int cg = bx & 63;
  const int m16 = lane & 15;
  const int kl = (lane >> 4) * 8;
  const int rsub = (lane >> 4) * 4;
  const int swzA = (m16 & 7) << 4;

  // ---- init h_own; publish h_pairs at t0==0 ----
  {
    int row = tid >> 3, pp = tid & 7;  // 128 threads = 16 rows x 8 pairs
    int col = cg * 16 + pp * 2;
    int grow = rg * 16 + row;
    float v0, v1;
    if (t0 == 0) {
      v0 = h0[((size_t)grow * 2 + layer) * H_ + col];
      v1 = h0[((size_t)grow * 2 + layer) * H_ + col + 1];
      coh_st(h_pairs + grow * 512 + (col >> 1), f2bf_bits(v0) | (f2bf_bits(v1) << 16));
    } else {
      v0 = h_f32[grow * H_ + col];
      v1 = h_f32[grow * H_ + col + 1];
    }
    h_own[row * 17 + pp * 2] = v0;
    h_own[row * 17 + pp * 2 + 1] = v1;
  }
  u32 bk = ep0 + 1;
  gbar(ctr, bk * NBLK);

  const u32* hp_src = h_pairs + rg * (16 * 512);
  const u32* rh_src = rh_pairs + rg * (16 * 512);

  for (int t = 0; t < TC_; ++t) {
    // ================= phase A: z (wave0) / r -> rh (wave1) ================
    const int colA = cg * 16 + m16 + ((w == 1) ? H_ : 0);
    float xpv[4];
#pragma unroll
    for (int j = 0; j < 4; ++j) {
      int grow = rg * 16 + rsub + j;
      xpv[j] = xp[((size_t)(grow * TC_ + t)) * H3_ + colA];
    }
    stage16(hp_src, stage, tid);
    __syncthreads();
    {
      f32x4 acc0 = {}, acc1 = {};
      const char* abase = stage + m16 * 2048;
      const __hip_bfloat16* Bb = Wh + (size_t)colA * H_;
#pragma unroll
      for (int k0 = 0; k0 < H_; k0 += 64) {
        bf16x8 a0 = *(const bf16x8*)(abase + (((k0 + kl) * 2) ^ swzA));
        bf16x8 a1 = *(const bf16x8*)(abase + (((k0 + 32 + kl) * 2) ^ swzA));
        bf16x8 b0 = *(const bf16x8*)(Bb + k0 + kl);
        bf16x8 b1 = *(const bf16x8*)(Bb + k0 + 32 + kl);
        acc0 = __builtin_amdgcn_mfma_f32_16x16x32_bf16(a0, b0, acc0, 0, 0, 0);
        acc1 = __builtin_amdgcn_mfma_f32_16x16x32_bf16(a1, b1, acc1, 0, 0, 0);
      }
      if (w == 0) {
#pragma unroll
        for (int j = 0; j < 4; ++j) {
          float pre = acc0[j] + acc1[j] + xpv[j];
          z_own[(rsub + j) * 17 + m16] = 1.f / (1.f + expf(-pre));
        }
      } else {
#pragma unroll
        for (int j = 0; j < 4; ++j) {
          int lr = rsub + j;
          float pre = acc0[j] + acc1[j] + xpv[j];
          float s = 1.f / (1.f + expf(-pre));
          float rh = s * h_own[lr * 17 + m16];
          u32 bits = f2bf_bits(rh);
          u32 pair = bits | (((u32)__shfl_down((int)bits, 1)) << 16);
          if ((m16 & 1) == 0)
            coh_st(rh_pairs + (size_t)(rg * 16 + lr) * 512 + ((cg * 16 + m16) >> 1), pair);
        }
      }
    }
    ++bk;
    gbar(ctr, bk * NBLK);

    // ================= phase B: g + h update (wave0) =======================
    float xpg[4];
    if (w == 0) {
#pragma unroll
      for (int j = 0; j < 4; ++j) {
        int grow = rg * 16 + rsub + j;
        xpg[j] = xp[((size_t)(grow * TC_ + t)) * H3_ + 2 * H_ + cg * 16 + m16];
      }
    }
    stage16(rh_src, stage, tid);
    __syncthreads();
    if (w == 0) {
      f32x4 acc0 = {}, acc1 = {};
      const char* abase = stage + m16 * 2048;
      const __hip_bfloat16* Bb = Wh + (size_t)(2 * H_ + cg * 16 + m16) * H_;
#pragma unroll
      for (int k0 = 0; k0 < H_; k0 += 64) {
        bf16x8 a0 = *(const bf16x8*)(abase + (((k0 + kl) * 2) ^ swzA));
        bf16x8 a1 = *(const bf16x8*)(abase + (((k0 + 32 + kl) * 2) ^ swzA));
        bf16x8 b0 = *(const bf16x8*)(Bb + k0 + kl);
        bf16x8 b1 = *(const bf16x8*)(Bb + k0 + 32 + kl);
        acc0 = __builtin_amdgcn_mfma_f32_16x16x32_bf16(a0, b0, acc0, 0, 0, 0);
        acc1 = __builtin_amdgcn_mfma_f32_16x16x32_bf16(a1, b1, acc1, 0, 0, 0);
      }
#pragma unroll
      for (int j = 0; j < 4; ++j) {
        int lr = rsub + j;
        float pre = acc0[j] + acc1[j] + xpg[j];
        float gg = tanhf(pre);
        float zz = z_own[lr * 17 + m16];
        float hv = h_own[lr * 17 + m16];
        float hn = zz * hv + (1.f - zz) * gg;
        h_own[lr * 17 + m16] = hn;
        u32 bits = f2bf_bits(hn);
        u32 pair = bits | (((u32)__shfl_down((int)bits, 1)) << 16);
        if ((m16 & 1) == 0)
          coh_st(h_pairs + (size_t)(rg * 16 + lr) * 512 + ((cg * 16 + m16) >> 1), pair);
        y[((size_t)((rg * 16 + lr) * TC_ + t)) * H_ + cg * 16 + m16] = __float2bfloat16(hn);
      }
    }
    ++bk;
    gbar(ctr, bk * NBLK);
  }

  // ---- persist h_own (last gbar's syncthreads ordered wave0's writes) ----
  {
    int row = tid >> 3, pp = tid & 7;
    int col = cg * 16 + pp * 2;
    int grow = rg * 16 + row;
    float v0 = h_own[row * 17 + pp * 2];
    float v1 = h_own[row * 17 + pp * 2 + 1];
    h_f32[grow * H_ + col] = v0;
    h_f32[grow * H_ + col + 1] = v1;
    if (t0 + TC_ == S_) {
      hid_out[((size_t)grow * 2 + layer) * H_ + col] = v0;
      hid_out[((size_t)grow * 2 + layer) * H_ + col + 1] = v1;
    }
  }
}

// ---------------------------------------------------------------------------
extern "C" void kernel_launch(void* const* d_in, const int* in_sizes, int n_in,
                              void* d_out, int out_size, void* d_ws, size_t ws_size,
                              hipStream_t stream) {
  const float* x   = (const float*)d_in[0];
  const float* h0  = (const float*)d_in[1];
  const float* Wx0 = (const float*)d_in[2];
  const float* Wh0 = (const float*)d_in[3];
  const float* bh0 = (const float*)d_in[4];
  const float* Wx1 = (const float*)d_in[5];
  const float* Wh1 = (const float*)d_in[6];
  const float* bh1 = (const float*)d_in[7];
  const float* Why = (const float*)d_in[8];
  const float* by  = (const float*)d_in[9];
  float* out = (float*)d_out;
  float* hid_out = out + (size_t)NROW * OUT_;

  hipFuncSetAttribute((const void*)gru_scan_chunk,
                      hipFuncAttributeMaxDynamicSharedMemorySize, SMEM_BYTES);

  char* ws = (char*)d_ws;
  size_t off = 0;
  auto alloc = [&](size_t bytes) {
    char* p = ws + off;
    off += (bytes + 255) & ~(size_t)255;
    return p;
  };
  __hip_bfloat16* wx0b = (__hip_bfloat16*)alloc((size_t)H3_ * IN_ * 2);
  __hip_bfloat16* wh0b = (__hip_bfloat16*)alloc((size_t)H3_ * H_ * 2);
  __hip_bfloat16* wx1b = (__hip_bfloat16*)alloc((size_t)H3_ * H_ * 2);
  __hip_bfloat16* wh1b = (__hip_bfloat16*)alloc((size_t)H3_ * H_ * 2);
  __hip_bfloat16* whyb = (__hip_bfloat16*)alloc((size_t)OUT_ * H_ * 2);
  float* h_f32_0 = (float*)alloc((size_t)B_ * H_ * 4);
  float* h_f32_1 = (float*)alloc((size_t)B_ * H_ * 4);
  u32* h_pairs_0 = (u32*)alloc((size_t)B_ * 512 * 4);
  u32* h_pairs_1 = (u32*)alloc((size_t)B_ * 512 * 4);
  u32* rh_pairs  = (u32*)alloc((size_t)B_ * 512 * 4);
  __hip_bfloat16* x_bfc = (__hip_bfloat16*)alloc((size_t)MC_ * IN_ * 2);
  __hip_bfloat16* y_c   = (__hip_bfloat16*)alloc((size_t)MC_ * H_ * 2);
  float* xp_c           = (float*)alloc((size_t)MC_ * H3_ * 4);
  u32* ctr              = (u32*)alloc(256);
  (void)ws_size;

  hipMemsetAsync(ctr, 0, 4, stream);

  auto cast = [&](const float* in, __hip_bfloat16* o, size_t n) {
    cast_f32_to_bf16<<<dim3((unsigned)((n / 4 + 255) / 256)), dim3(256), 0, stream>>>(in, o,
                                                                                     (int)(n / 4));
  };
  cast(Wx0, wx0b, (size_t)H3_ * IN_);
  cast(Wh0, wh0b, (size_t)H3_ * H_);
  cast(Wx1, wx1b, (size_t)H3_ * H_);
  cast(Wh1, wh1b, (size_t)H3_ * H_);
  cast(Why, whyb, (size_t)OUT_ * H_);

  const u32 EPK = 1 + 2 * TC_;  // barriers per scan dispatch

  // cooperative launch preferred (co-residency guarantee); deterministic
  // fallback to plain launch (our barrier never uses cg::grid_group).
  auto launch_scan = [&](const float* xpp, const __hip_bfloat16* whb, float* hf, u32* hp,
                         int layer, int t0, u32 ep0) {
    void* args[] = {(void*)&xpp,      (void*)&h0,  (void*)&layer,   (void*)&t0,
                    (void*)&whb,      (void*)&hf,  (void*)&hp,
                    (void*)&rh_pairs, (void*)&y_c, (void*)&hid_out, (void*)&ctr,
                    (void*)&ep0};
    hipError_t e = hipLaunchCooperativeKernel((void*)gru_scan_chunk, dim3(NBLK), dim3(NTHR), args,
                                              SMEM_BYTES, stream);
    if (e != hipSuccess) {
      (void)hipGetLastError();  // clear sticky error
      gru_scan_chunk<<<dim3(NBLK), dim3(NTHR), SMEM_BYTES, stream>>>(
          xpp, h0, layer, t0, whb, hf, hp, rh_pairs, y_c, hid_out, ctr, ep0);
    }
  };

  for (int c = 0; c < NCHUNK; ++c) {
    int t0 = c * TC_;
    gather_cast_x<<<dim3(MC_ * IN_ / 4 / 256), dim3(256), 0, stream>>>(x, x_bfc, t0);
    gemm_nt_bias<false><<<dim3(H3_ / 128, MC_ / 128), dim3(256), 0, stream>>>(
        x_bfc, wx0b, bh0, xp_c, MC_, H3_, IN_, 0);
    launch_scan(xp_c, wh0b, h_f32_0, h_pairs_0, 0, t0, (u32)(2 * c + 0) * EPK);
    gemm_nt_bias<false><<<dim3(H3_ / 128, MC_ / 128), dim3(256), 0, stream>>>(
        y_c, wx1b, bh1, xp_c, MC_, H3_, H_, 0);
    launch_scan(xp_c, wh1b, h_f32_1, h_pairs_1, 1, t0, (u32)(2 * c + 1) * EPK);
    gemm_nt_bias<true><<<dim3(OUT_ / 128, MC_ / 128), dim3(256), 0, stream>>>(
        y_c, whyb, by, out, MC_, OUT_, H_, t0);
  }
}